// Round 3
// baseline (1129.998 us; speedup 1.0000x reference)
//
#include <hip/hip_runtime.h>
#include <hip/hip_bf16.h>
#include <type_traits>

typedef __bf16 bf16_t;
typedef __attribute__((ext_vector_type(8))) __bf16 bf16x8;
typedef __attribute__((ext_vector_type(4))) float f32x4;

#define B_ 2
#define S_ 2048
#define D_ 1024
#define H_ 16
#define DK_ 64

enum { OM_F32 = 0, OM_BF16 = 1, OM_SPLIT = 2, OM_HEADT = 3 };

// split a run of 8 fp32 into bf16 hi + bf16 lo (residual) parts
__device__ inline void split8(const float* __restrict__ p, bf16x8& h, bf16x8& l) {
    float4 x0 = *(const float4*)p;
    float4 x1 = *(const float4*)(p + 4);
    float xs[8] = {x0.x, x0.y, x0.z, x0.w, x1.x, x1.y, x1.z, x1.w};
#pragma unroll
    for (int i = 0; i < 8; ++i) {
        bf16_t hh = (bf16_t)xs[i];
        h[i] = hh;
        l[i] = (bf16_t)(xs[i] - (float)hh);
    }
}
__device__ inline void hi8(const float* __restrict__ p, bf16x8& h) {
    float4 x0 = *(const float4*)p;
    float4 x1 = *(const float4*)(p + 4);
    float xs[8] = {x0.x, x0.y, x0.z, x0.w, x1.x, x1.y, x1.z, x1.w};
#pragma unroll
    for (int i = 0; i < 8; ++i) h[i] = (bf16_t)xs[i];
}

// ---------------------------------------------------------------------------
// GEMM: Y[M,N] = A[M,K] @ W[N,K]^T + bias[N].
// OMODE: F32 / BF16 / SPLIT (hi+lo bf16) / HEADT (bf16 [B,H,DK,S], via an
// LDS 64x64 tile transpose so global stores are coalesced 128B runs —
// the previous direct-scatter version issued 64x 2B transactions per store).
// ---------------------------------------------------------------------------
template <typename AT, int OMODE, bool SPLIT>
__global__ __launch_bounds__(256) void gemm_bt(
    const AT* __restrict__ A,
    const float* __restrict__ W,
    const float* __restrict__ bias,
    void* __restrict__ Yp,
    void* __restrict__ Y2p,
    int M, int N, int K)
{
    const int NB = N >> 6;
    const int bm = blockIdx.x / NB;
    const int bn = blockIdx.x % NB;
    const int tid  = threadIdx.x;
    const int wave = tid >> 6;
    const int lane = tid & 63;
    const int l16  = lane & 15;
    const int quad = lane >> 4;
    const int wm = wave >> 1, wn = wave & 1;

    __shared__ bf16_t Ah[64][40];
    __shared__ bf16_t Wh[64][40];
    __shared__ bf16_t Al[SPLIT ? 64 : 1][40];
    __shared__ bf16_t Wl[SPLIT ? 64 : 1][40];
    __shared__ bf16_t T[OMODE == OM_HEADT ? 64 : 1][72];  // [dk][ss]

    const int srow = tid >> 2;        // 0..63
    const int scol = (tid & 3) * 8;   // 0,8,16,24

    f32x4 acc[2][2];
#pragma unroll
    for (int i = 0; i < 2; ++i)
#pragma unroll
        for (int j = 0; j < 2; ++j) acc[i][j] = (f32x4){0.f, 0.f, 0.f, 0.f};

    const AT*    Arow = A + (size_t)(bm * 64 + srow) * K + scol;
    const float* Wrow = W + (size_t)(bn * 64 + srow) * K + scol;

    for (int k0 = 0; k0 < K; k0 += 32) {
        if constexpr (std::is_same_v<AT, float>) {
            bf16x8 ah, al;
            if constexpr (SPLIT) {
                split8(Arow + k0, ah, al);
                *(bf16x8*)(&Al[srow][scol]) = al;
            } else {
                hi8(Arow + k0, ah);
            }
            *(bf16x8*)(&Ah[srow][scol]) = ah;
        } else {
            *(bf16x8*)(&Ah[srow][scol]) = *(const bf16x8*)(Arow + k0);
        }
        {
            bf16x8 wh, wl;
            if constexpr (SPLIT) {
                split8(Wrow + k0, wh, wl);
                *(bf16x8*)(&Wl[srow][scol]) = wl;
            } else {
                hi8(Wrow + k0, wh);
            }
            *(bf16x8*)(&Wh[srow][scol]) = wh;
        }
        __syncthreads();

        bf16x8 afh[2], bfh[2], afl[2], bfl[2];
#pragma unroll
        for (int mi = 0; mi < 2; ++mi) {
            afh[mi] = *(const bf16x8*)(&Ah[wm * 32 + mi * 16 + l16][quad * 8]);
            if constexpr (SPLIT)
                afl[mi] = *(const bf16x8*)(&Al[wm * 32 + mi * 16 + l16][quad * 8]);
        }
#pragma unroll
        for (int ni = 0; ni < 2; ++ni) {
            bfh[ni] = *(const bf16x8*)(&Wh[wn * 32 + ni * 16 + l16][quad * 8]);
            if constexpr (SPLIT)
                bfl[ni] = *(const bf16x8*)(&Wl[wn * 32 + ni * 16 + l16][quad * 8]);
        }

#pragma unroll
        for (int mi = 0; mi < 2; ++mi)
#pragma unroll
            for (int ni = 0; ni < 2; ++ni) {
                acc[mi][ni] = __builtin_amdgcn_mfma_f32_16x16x32_bf16(
                    afh[mi], bfh[ni], acc[mi][ni], 0, 0, 0);
                if constexpr (SPLIT) {
                    acc[mi][ni] = __builtin_amdgcn_mfma_f32_16x16x32_bf16(
                        afl[mi], bfh[ni], acc[mi][ni], 0, 0, 0);
                    acc[mi][ni] = __builtin_amdgcn_mfma_f32_16x16x32_bf16(
                        afh[mi], bfl[ni], acc[mi][ni], 0, 0, 0);
                }
            }
        __syncthreads();
    }

    if constexpr (OMODE == OM_HEADT) {
        // stage transposed tile in LDS: T[dk][ss_local]
#pragma unroll
        for (int ni = 0; ni < 2; ++ni) {
            const int cl = wn * 32 + ni * 16 + l16;          // dk
            const float bv = bias[bn * 64 + cl];
#pragma unroll
            for (int mi = 0; mi < 2; ++mi)
#pragma unroll
                for (int r = 0; r < 4; ++r) {
                    const int rl = wm * 32 + mi * 16 + quad * 4 + r;  // ss
                    T[cl][rl] = (bf16_t)(acc[mi][ni][r] + bv);
                }
        }
        __syncthreads();
        // coalesced store: vt[(b*H + bn)*DK + dk][ss0 + ss_off]
        const int bb  = bm >> 5;                 // row/S_
        const int ss0 = (bm * 64) & (S_ - 1);
#pragma unroll
        for (int it = 0; it < 2; ++it) {
            const int dk = it * 32 + (tid >> 3);
            const int so = (tid & 7) * 8;
            *(bf16x8*)((bf16_t*)Yp +
                ((size_t)((bb * H_ + bn) * DK_ + dk) << 11) + ss0 + so) =
                *(const bf16x8*)(&T[dk][so]);
        }
        return;
    }

#pragma unroll
    for (int ni = 0; ni < 2; ++ni) {
        const int col = bn * 64 + wn * 32 + ni * 16 + l16;
        const float bv = bias[col];
#pragma unroll
        for (int mi = 0; mi < 2; ++mi) {
#pragma unroll
            for (int r = 0; r < 4; ++r) {
                const int row = bm * 64 + wm * 32 + mi * 16 + quad * 4 + r;
                const float v = acc[mi][ni][r] + bv;
                if constexpr (OMODE == OM_F32) {
                    ((float*)Yp)[(size_t)row * N + col] = v;
                } else if constexpr (OMODE == OM_BF16) {
                    ((bf16_t*)Yp)[(size_t)row * N + col] = (bf16_t)v;
                } else if constexpr (OMODE == OM_SPLIT) {
                    const bf16_t hh = (bf16_t)v;
                    ((bf16_t*)Yp)[(size_t)row * N + col] = hh;
                    ((bf16_t*)Y2p)[(size_t)row * N + col] = (bf16_t)(v - (float)hh);
                }
            }
        }
    }
}

// ---------------------------------------------------------------------------
// Pack the int32 mask [B,S,S] into bits (1 = masked). One u64 per 64 j's.
// ---------------------------------------------------------------------------
__global__ __launch_bounds__(256) void pack_mask(
    const int* __restrict__ mask,
    unsigned long long* __restrict__ pk)
{
    const size_t nwords = (size_t)B_ * S_ * S_ / 64;  // 131072
    const int lane = threadIdx.x & 63;
    size_t w = (size_t)blockIdx.x * 4 + (threadIdx.x >> 6);
    const size_t stride = (size_t)gridDim.x * 4;
    for (; w < nwords; w += stride) {
        const int m = mask[w * 64 + lane];
        const unsigned long long bb = __ballot(m != 0);
        if (lane == 0) pk[w] = bb;
    }
}

// ---------------------------------------------------------------------------
// Kernel A: scores only. QK^T (hi/lo split, 6 MFMA), exp, UNNORMALIZED e ->
// wout, lsum -> normbuf. JT=64 (2 barriers per 64 j). No PV work.
// ---------------------------------------------------------------------------
__global__ __launch_bounds__(256) void attn_scores(
    const bf16_t* __restrict__ qh_g,
    const bf16_t* __restrict__ ql_g,
    const bf16_t* __restrict__ kh_g,
    const bf16_t* __restrict__ kl_g,
    const unsigned long long* __restrict__ pm,  // [B,S,S/64]
    float* __restrict__ wout,                   // unnormalized e
    float* __restrict__ normbuf)                // [B,H,S]
{
    const int bid = blockIdx.x;       // 1024
    const int qt = bid & 31;
    const int h  = (bid >> 5) & 15;
    const int b  = bid >> 9;
    const int tid  = threadIdx.x;
    const int wave = tid >> 6;
    const int lane = tid & 63;
    const int l16  = lane & 15;
    const int quad = lane >> 4;

    const int q0 = qt * 64 + wave * 16;

    __shared__ bf16_t Kh[64][72];
    __shared__ bf16_t Kl[64][72];

    const size_t qoff = ((size_t)(b * S_ + q0 + l16)) * D_ + h * DK_ + quad * 8;
    const bf16x8 qh0 = *(const bf16x8*)(qh_g + qoff);
    const bf16x8 qh1 = *(const bf16x8*)(qh_g + qoff + 32);
    const bf16x8 ql0 = *(const bf16x8*)(ql_g + qoff);
    const bf16x8 ql1 = *(const bf16x8*)(ql_g + qoff + 32);

    const float scale = 0.125f;

    const int srow = tid >> 2;        // 0..63 (j)
    const int scol = (tid & 3) * 16;  // 0,16,32,48 (dk)
    const bf16_t* khst = kh_g + (size_t)b * S_ * D_ + h * DK_;
    const bf16_t* klst = kl_g + (size_t)b * S_ * D_ + h * DK_;

    const unsigned long long* pmrow = pm + (size_t)b * S_ * (S_ / 64);
    const size_t wbase = ((size_t)(b * H_ + h)) * S_ * S_;

    float lsum[4] = {0.f, 0.f, 0.f, 0.f};

    for (int j0 = 0; j0 < S_; j0 += 64) {
        {
            const size_t ko = (size_t)(j0 + srow) * D_ + scol;
            *(bf16x8*)(&Kh[srow][scol])     = *(const bf16x8*)(khst + ko);
            *(bf16x8*)(&Kh[srow][scol + 8]) = *(const bf16x8*)(khst + ko + 8);
            *(bf16x8*)(&Kl[srow][scol])     = *(const bf16x8*)(klst + ko);
            *(bf16x8*)(&Kl[srow][scol + 8]) = *(const bf16x8*)(klst + ko + 8);
        }
        unsigned long long mw[4];
#pragma unroll
        for (int r = 0; r < 4; ++r) {
            const int q = q0 + quad * 4 + r;
            mw[r] = pmrow[(size_t)q * (S_ / 64) + (j0 >> 6)];
        }
        __syncthreads();

#pragma unroll
        for (int sub = 0; sub < 4; ++sub) {
            const int rr = sub * 16 + l16;
            const bf16x8 kh0 = *(const bf16x8*)(&Kh[rr][quad * 8]);
            const bf16x8 kh1 = *(const bf16x8*)(&Kh[rr][32 + quad * 8]);
            const bf16x8 kl0 = *(const bf16x8*)(&Kl[rr][quad * 8]);
            const bf16x8 kl1 = *(const bf16x8*)(&Kl[rr][32 + quad * 8]);
            f32x4 c = (f32x4){0.f, 0.f, 0.f, 0.f};
            c = __builtin_amdgcn_mfma_f32_16x16x32_bf16(qh0, kh0, c, 0, 0, 0);
            c = __builtin_amdgcn_mfma_f32_16x16x32_bf16(qh1, kh1, c, 0, 0, 0);
            c = __builtin_amdgcn_mfma_f32_16x16x32_bf16(ql0, kh0, c, 0, 0, 0);
            c = __builtin_amdgcn_mfma_f32_16x16x32_bf16(ql1, kh1, c, 0, 0, 0);
            c = __builtin_amdgcn_mfma_f32_16x16x32_bf16(qh0, kl0, c, 0, 0, 0);
            c = __builtin_amdgcn_mfma_f32_16x16x32_bf16(qh1, kl1, c, 0, 0, 0);
            const int jt = j0 + sub * 16;
#pragma unroll
            for (int r = 0; r < 4; ++r) {
                const int q = q0 + quad * 4 + r;
                const int msk = (int)((mw[r] >> (sub * 16 + l16)) & 1ull);
                const float e = msk ? 0.f : __expf(c[r] * scale);
                lsum[r] += e;
                __builtin_nontemporal_store(e, &wout[wbase + (size_t)q * S_ + jt + l16]);
            }
        }
        __syncthreads();
    }

#pragma unroll
    for (int r = 0; r < 4; ++r) {
        float v = lsum[r];
        v += __shfl_xor(v, 1);
        v += __shfl_xor(v, 2);
        v += __shfl_xor(v, 4);
        v += __shfl_xor(v, 8);
        lsum[r] = v;
    }
    if (l16 == 0) {
#pragma unroll
        for (int r = 0; r < 4; ++r)
            normbuf[(size_t)(b * H_ + h) * S_ + q0 + quad * 4 + r] = 2048.f / lsum[r];
    }
}

// ---------------------------------------------------------------------------
// Kernel B: rescale + PV fused. Reads unnormalized e (537 MB), writes
// normalized w in place (537 MB) — same traffic as the old rescale kernel —
// and performs the PV MFMAs under that BW-bound stream (compute hidden).
// Numerics bit-identical to previous round: MFMA uses bf16(e) unnormalized,
// acc scaled by norm at the end; wout = e * norm in fp32.
// ---------------------------------------------------------------------------
__global__ __launch_bounds__(256) void attn_pv(
    const bf16_t* __restrict__ vt_g,   // [B,H,DK,S]
    const float*  __restrict__ normbuf,
    float* __restrict__ wout,          // in: e, out: w (in place)
    bf16_t* __restrict__ ctx)          // [B,S,D]
{
    const int bid = blockIdx.x;       // 1024
    const int qt = bid & 31;
    const int h  = (bid >> 5) & 15;
    const int b  = bid >> 9;
    const int tid  = threadIdx.x;
    const int wave = tid >> 6;
    const int lane = tid & 63;
    const int l16  = lane & 15;
    const int quad = lane >> 4;

    const int q0 = qt * 64 + wave * 16;

    __shared__ bf16_t vT[64][72];      // [dk][j] tile, JT=64

    const int sdk = tid >> 2;          // 0..63
    const int sjo = (tid & 3) * 16;    // 0,16,32,48
    const bf16_t* vtst = vt_g + ((size_t)(b * H_ + h) * DK_ + sdk) * S_ + sjo;

    const size_t wbase = ((size_t)(b * H_ + h)) * S_ * S_;
    const float nrmA = normbuf[(size_t)(b * H_ + h) * S_ + q0 + l16];  // row l16
    float norm_c[4];
#pragma unroll
    for (int r = 0; r < 4; ++r)
        norm_c[r] = normbuf[(size_t)(b * H_ + h) * S_ + q0 + quad * 4 + r];

    f32x4 acc[4];
#pragma unroll
    for (int t = 0; t < 4; ++t) acc[t] = (f32x4){0.f, 0.f, 0.f, 0.f};

    float* wrow = wout + wbase + (size_t)(q0 + l16) * S_;

    for (int j0 = 0; j0 < S_; j0 += 64) {
        {
            *(bf16x8*)(&vT[sdk][sjo])     = *(const bf16x8*)(vtst + j0);
            *(bf16x8*)(&vT[sdk][sjo + 8]) = *(const bf16x8*)(vtst + j0 + 8);
        }
        __syncthreads();

#pragma unroll
        for (int half = 0; half < 2; ++half) {
            const int jj = j0 + half * 32 + quad * 8;
            float* ep = wrow + jj;
            float4 e0, e1;
            e0.x = __builtin_nontemporal_load(ep + 0);
            e0.y = __builtin_nontemporal_load(ep + 1);
            e0.z = __builtin_nontemporal_load(ep + 2);
            e0.w = __builtin_nontemporal_load(ep + 3);
            e1.x = __builtin_nontemporal_load(ep + 4);
            e1.y = __builtin_nontemporal_load(ep + 5);
            e1.z = __builtin_nontemporal_load(ep + 6);
            e1.w = __builtin_nontemporal_load(ep + 7);
            const float es[8] = {e0.x, e0.y, e0.z, e0.w, e1.x, e1.y, e1.z, e1.w};
            bf16x8 wa;
#pragma unroll
            for (int i = 0; i < 8; ++i) {
                __builtin_nontemporal_store(es[i] * nrmA, ep + i);
                wa[i] = (bf16_t)es[i];   // unnormalized, as before
            }
#pragma unroll
            for (int t = 0; t < 4; ++t) {
                const bf16x8 vf = *(const bf16x8*)(&vT[t * 16 + l16][half * 32 + quad * 8]);
                acc[t] = __builtin_amdgcn_mfma_f32_16x16x32_bf16(wa, vf, acc[t], 0, 0, 0);
            }
        }
        __syncthreads();
    }

#pragma unroll
    for (int t = 0; t < 4; ++t) {
#pragma unroll
        for (int r = 0; r < 4; ++r) {
            const int q = q0 + quad * 4 + r;
            ctx[((size_t)(b * S_ + q)) * D_ + h * DK_ + t * 16 + l16] =
                (bf16_t)(acc[t][r] * norm_c[r]);
        }
    }
}

// ---------------------------------------------------------------------------
extern "C" void kernel_launch(void* const* d_in, const int* in_sizes, int n_in,
                              void* d_out, int out_size, void* d_ws, size_t ws_size,
                              hipStream_t stream) {
    const float* Q    = (const float*)d_in[0];
    const float* K    = (const float*)d_in[1];
    const float* V    = (const float*)d_in[2];
    const int*   mask = (const int*)d_in[3];
    const float* Wq   = (const float*)d_in[4];
    const float* bq   = (const float*)d_in[5];
    const float* Wk   = (const float*)d_in[6];
    const float* bk   = (const float*)d_in[7];
    const float* Wv   = (const float*)d_in[8];
    const float* bv   = (const float*)d_in[9];
    const float* Wo   = (const float*)d_in[10];
    const float* bo   = (const float*)d_in[11];

    const size_t BSD = (size_t)B_ * S_ * D_;  // 4,194,304
    float* out  = (float*)d_out;              // [B,S,D] fp32
    float* wout = out + BSD;                  // [B,H,S,S] fp32

    bf16_t* qh = (bf16_t*)d_ws;
    bf16_t* ql = qh + BSD;
    bf16_t* kh = ql + BSD;
    bf16_t* kl = kh + BSD;
    bf16_t* vt = kl + BSD;
    bf16_t* cx = vt + BSD;
    unsigned long long* pk = (unsigned long long*)(cx + BSD);   // 1 MB
    float* normbuf = (float*)(pk + (size_t)B_ * S_ * (S_ / 64)); // 256 KB

    const int M = B_ * S_;   // 4096
    const int N = D_;        // 1024
    const int Kd = D_;       // 1024
    const dim3 ggrid((M / 64) * (N / 64));    // 1024
    const dim3 gblk(256);

    pack_mask<<<dim3(512), gblk, 0, stream>>>(mask, pk);

    gemm_bt<float, OM_SPLIT, true><<<ggrid, gblk, 0, stream>>>(Q, Wq, bq, qh, ql, M, N, Kd);
    gemm_bt<float, OM_SPLIT, true><<<ggrid, gblk, 0, stream>>>(K, Wk, bk, kh, kl, M, N, Kd);
    gemm_bt<float, OM_HEADT, false><<<ggrid, gblk, 0, stream>>>(V, Wv, bv, vt, nullptr, M, N, Kd);

    attn_scores<<<dim3(B_ * H_ * (S_ / 64)), gblk, 0, stream>>>(
        qh, ql, kh, kl, pk, wout, normbuf);

    attn_pv<<<dim3(B_ * H_ * (S_ / 64)), gblk, 0, stream>>>(
        vt, normbuf, wout, cx);

    gemm_bt<bf16_t, OM_F32, false><<<ggrid, gblk, 0, stream>>>(cx, Wo, bo, out, nullptr, M, N, Kd);
}

// Round 4
// 929.391 us; speedup vs baseline: 1.2158x; 1.2158x over previous
//
#include <hip/hip_runtime.h>
#include <hip/hip_bf16.h>
#include <type_traits>

typedef __bf16 bf16_t;
typedef __attribute__((ext_vector_type(8))) __bf16 bf16x8;
typedef __attribute__((ext_vector_type(4))) float f32x4;

#define B_ 2
#define S_ 2048
#define D_ 1024
#define H_ 16
#define DK_ 64

enum { OM_F32 = 0, OM_BF16 = 1, OM_SPLIT = 2, OM_HEADT = 3 };

// split a run of 8 fp32 into bf16 hi + bf16 lo (residual) parts
__device__ inline void split8(const float* __restrict__ p, bf16x8& h, bf16x8& l) {
    float4 x0 = *(const float4*)p;
    float4 x1 = *(const float4*)(p + 4);
    float xs[8] = {x0.x, x0.y, x0.z, x0.w, x1.x, x1.y, x1.z, x1.w};
#pragma unroll
    for (int i = 0; i < 8; ++i) {
        bf16_t hh = (bf16_t)xs[i];
        h[i] = hh;
        l[i] = (bf16_t)(xs[i] - (float)hh);
    }
}
__device__ inline void hi8(const float* __restrict__ p, bf16x8& h) {
    float4 x0 = *(const float4*)p;
    float4 x1 = *(const float4*)(p + 4);
    float xs[8] = {x0.x, x0.y, x0.z, x0.w, x1.x, x1.y, x1.z, x1.w};
#pragma unroll
    for (int i = 0; i < 8; ++i) h[i] = (bf16_t)xs[i];
}

// ---------------------------------------------------------------------------
// GEMM: Y[M,N] = A[M,K] @ W[N,K]^T + bias[N].
// OMODE: F32 / BF16 / SPLIT (hi+lo bf16) / HEADT (bf16 [B,H,DK,S], via an
// LDS 64x64 tile transpose so global stores are coalesced 128B runs).
// ---------------------------------------------------------------------------
template <typename AT, int OMODE, bool SPLIT>
__global__ __launch_bounds__(256) void gemm_bt(
    const AT* __restrict__ A,
    const float* __restrict__ W,
    const float* __restrict__ bias,
    void* __restrict__ Yp,
    void* __restrict__ Y2p,
    int M, int N, int K)
{
    const int NB = N >> 6;
    const int bm = blockIdx.x / NB;
    const int bn = blockIdx.x % NB;
    const int tid  = threadIdx.x;
    const int wave = tid >> 6;
    const int lane = tid & 63;
    const int l16  = lane & 15;
    const int quad = lane >> 4;
    const int wm = wave >> 1, wn = wave & 1;

    __shared__ bf16_t Ah[64][40];
    __shared__ bf16_t Wh[64][40];
    __shared__ bf16_t Al[SPLIT ? 64 : 1][40];
    __shared__ bf16_t Wl[SPLIT ? 64 : 1][40];
    __shared__ bf16_t T[OMODE == OM_HEADT ? 64 : 1][72];  // [dk][ss]

    const int srow = tid >> 2;        // 0..63
    const int scol = (tid & 3) * 8;   // 0,8,16,24

    f32x4 acc[2][2];
#pragma unroll
    for (int i = 0; i < 2; ++i)
#pragma unroll
        for (int j = 0; j < 2; ++j) acc[i][j] = (f32x4){0.f, 0.f, 0.f, 0.f};

    const AT*    Arow = A + (size_t)(bm * 64 + srow) * K + scol;
    const float* Wrow = W + (size_t)(bn * 64 + srow) * K + scol;

    for (int k0 = 0; k0 < K; k0 += 32) {
        if constexpr (std::is_same_v<AT, float>) {
            bf16x8 ah, al;
            if constexpr (SPLIT) {
                split8(Arow + k0, ah, al);
                *(bf16x8*)(&Al[srow][scol]) = al;
            } else {
                hi8(Arow + k0, ah);
            }
            *(bf16x8*)(&Ah[srow][scol]) = ah;
        } else {
            *(bf16x8*)(&Ah[srow][scol]) = *(const bf16x8*)(Arow + k0);
        }
        {
            bf16x8 wh, wl;
            if constexpr (SPLIT) {
                split8(Wrow + k0, wh, wl);
                *(bf16x8*)(&Wl[srow][scol]) = wl;
            } else {
                hi8(Wrow + k0, wh);
            }
            *(bf16x8*)(&Wh[srow][scol]) = wh;
        }
        __syncthreads();

        bf16x8 afh[2], bfh[2], afl[2], bfl[2];
#pragma unroll
        for (int mi = 0; mi < 2; ++mi) {
            afh[mi] = *(const bf16x8*)(&Ah[wm * 32 + mi * 16 + l16][quad * 8]);
            if constexpr (SPLIT)
                afl[mi] = *(const bf16x8*)(&Al[wm * 32 + mi * 16 + l16][quad * 8]);
        }
#pragma unroll
        for (int ni = 0; ni < 2; ++ni) {
            bfh[ni] = *(const bf16x8*)(&Wh[wn * 32 + ni * 16 + l16][quad * 8]);
            if constexpr (SPLIT)
                bfl[ni] = *(const bf16x8*)(&Wl[wn * 32 + ni * 16 + l16][quad * 8]);
        }

#pragma unroll
        for (int mi = 0; mi < 2; ++mi)
#pragma unroll
            for (int ni = 0; ni < 2; ++ni) {
                acc[mi][ni] = __builtin_amdgcn_mfma_f32_16x16x32_bf16(
                    afh[mi], bfh[ni], acc[mi][ni], 0, 0, 0);
                if constexpr (SPLIT) {
                    acc[mi][ni] = __builtin_amdgcn_mfma_f32_16x16x32_bf16(
                        afl[mi], bfh[ni], acc[mi][ni], 0, 0, 0);
                    acc[mi][ni] = __builtin_amdgcn_mfma_f32_16x16x32_bf16(
                        afh[mi], bfl[ni], acc[mi][ni], 0, 0, 0);
                }
            }
        __syncthreads();
    }

    if constexpr (OMODE == OM_HEADT) {
        // stage transposed tile in LDS: T[dk][ss_local]
#pragma unroll
        for (int ni = 0; ni < 2; ++ni) {
            const int cl = wn * 32 + ni * 16 + l16;          // dk
            const float bv = bias[bn * 64 + cl];
#pragma unroll
            for (int mi = 0; mi < 2; ++mi)
#pragma unroll
                for (int r = 0; r < 4; ++r) {
                    const int rl = wm * 32 + mi * 16 + quad * 4 + r;  // ss
                    T[cl][rl] = (bf16_t)(acc[mi][ni][r] + bv);
                }
        }
        __syncthreads();
        // coalesced store: vt[(b*H + bn)*DK + dk][ss0 + ss_off]
        const int bb  = bm >> 5;                 // row/S_
        const int ss0 = (bm * 64) & (S_ - 1);
#pragma unroll
        for (int it = 0; it < 2; ++it) {
            const int dk = it * 32 + (tid >> 3);
            const int so = (tid & 7) * 8;
            *(bf16x8*)((bf16_t*)Yp +
                ((size_t)((bb * H_ + bn) * DK_ + dk) << 11) + ss0 + so) =
                *(const bf16x8*)(&T[dk][so]);
        }
        return;
    }

#pragma unroll
    for (int ni = 0; ni < 2; ++ni) {
        const int col = bn * 64 + wn * 32 + ni * 16 + l16;
        const float bv = bias[col];
#pragma unroll
        for (int mi = 0; mi < 2; ++mi) {
#pragma unroll
            for (int r = 0; r < 4; ++r) {
                const int row = bm * 64 + wm * 32 + mi * 16 + quad * 4 + r;
                const float v = acc[mi][ni][r] + bv;
                if constexpr (OMODE == OM_F32) {
                    ((float*)Yp)[(size_t)row * N + col] = v;
                } else if constexpr (OMODE == OM_BF16) {
                    ((bf16_t*)Yp)[(size_t)row * N + col] = (bf16_t)v;
                } else if constexpr (OMODE == OM_SPLIT) {
                    const bf16_t hh = (bf16_t)v;
                    ((bf16_t*)Yp)[(size_t)row * N + col] = hh;
                    ((bf16_t*)Y2p)[(size_t)row * N + col] = (bf16_t)(v - (float)hh);
                }
            }
        }
    }
}

// ---------------------------------------------------------------------------
// Pack the int32 mask [B,S,S] into bits (1 = masked). One u64 per 64 j's.
// ---------------------------------------------------------------------------
__global__ __launch_bounds__(256) void pack_mask(
    const int* __restrict__ mask,
    unsigned long long* __restrict__ pk)
{
    const size_t nwords = (size_t)B_ * S_ * S_ / 64;  // 131072
    const int lane = threadIdx.x & 63;
    size_t w = (size_t)blockIdx.x * 4 + (threadIdx.x >> 6);
    const size_t stride = (size_t)gridDim.x * 4;
    for (; w < nwords; w += stride) {
        const int m = mask[w * 64 + lane];
        const unsigned long long bb = __ballot(m != 0);
        if (lane == 0) pk[w] = bb;
    }
}

// ---------------------------------------------------------------------------
// Fused two-pass attention. Score recompute is cheap (QK^T = 51.5 GFLOP
// ~20us, exp ~10us); streaming unnormalized e through HBM was not (1.07 GB).
// Pass 1: QK^T + exp -> lsum only (no stores). Pass 2: identical recompute
// (bit-identical e), write w = e*norm ONCE (nontemporal fp32), PV with
// unnormalized bf16(e), scale acc by norm at the end. JT=64.
// ---------------------------------------------------------------------------
__global__ __launch_bounds__(256) void attn_kernel(
    const bf16_t* __restrict__ qh_g,   // [B,S,D] bf16 hi
    const bf16_t* __restrict__ ql_g,   // [B,S,D] bf16 lo
    const bf16_t* __restrict__ kh_g,   // [B,S,D] bf16 hi
    const bf16_t* __restrict__ kl_g,   // [B,S,D] bf16 lo
    const bf16_t* __restrict__ vt_g,   // [B,H,DK,S] bf16
    const unsigned long long* __restrict__ pm,  // [B,S,S/64] packed mask
    float* __restrict__ wout,          // [B,H,S,S] fp32 normalized weights
    bf16_t* __restrict__ ctx)          // [B,S,D] bf16
{
    const int bid = blockIdx.x;       // 1024
    const int qt = bid & 31;
    const int h  = (bid >> 5) & 15;
    const int b  = bid >> 9;
    const int tid  = threadIdx.x;
    const int wave = tid >> 6;
    const int lane = tid & 63;
    const int l16  = lane & 15;
    const int quad = lane >> 4;

    const int q0 = qt * 64 + wave * 16;

    __shared__ bf16_t Kh[64][72];
    __shared__ bf16_t Kl[64][72];
    __shared__ bf16_t vT[64][72];        // [dk][j]
    __shared__ bf16_t wl[4][16][72];     // per-wave w tile [q][j]

    // q fragments (A operand), hi/lo — live across both passes
    const size_t qoff = ((size_t)(b * S_ + q0 + l16)) * D_ + h * DK_ + quad * 8;
    const bf16x8 qh0 = *(const bf16x8*)(qh_g + qoff);
    const bf16x8 qh1 = *(const bf16x8*)(qh_g + qoff + 32);
    const bf16x8 ql0 = *(const bf16x8*)(ql_g + qoff);
    const bf16x8 ql1 = *(const bf16x8*)(ql_g + qoff + 32);

    const float scale = 0.125f;  // 1/sqrt(64)

    // cooperative staging indices (JT=64: 64 rows x 64 cols, 2x bf16x8/thread)
    const int srow = tid >> 2;        // 0..63
    const int scol = (tid & 3) * 16;  // 0,16,32,48
    const bf16_t* khst = kh_g + (size_t)b * S_ * D_ + h * DK_;
    const bf16_t* klst = kl_g + (size_t)b * S_ * D_ + h * DK_;
    const bf16_t* vtst = vt_g + ((size_t)(b * H_ + h) * DK_ + srow) * S_ + scol;

    const unsigned long long* pmrow = pm + (size_t)b * S_ * (S_ / 64);
    const size_t wbase = ((size_t)(b * H_ + h)) * S_ * S_;

    float lsum[4] = {0.f, 0.f, 0.f, 0.f};

    // ---------------- Pass 1: denominators only ----------------
    for (int j0 = 0; j0 < S_; j0 += 64) {
        {
            const size_t ko = (size_t)(j0 + srow) * D_ + scol;
            *(bf16x8*)(&Kh[srow][scol])     = *(const bf16x8*)(khst + ko);
            *(bf16x8*)(&Kh[srow][scol + 8]) = *(const bf16x8*)(khst + ko + 8);
            *(bf16x8*)(&Kl[srow][scol])     = *(const bf16x8*)(klst + ko);
            *(bf16x8*)(&Kl[srow][scol + 8]) = *(const bf16x8*)(klst + ko + 8);
        }
        unsigned long long mw[4];
#pragma unroll
        for (int r = 0; r < 4; ++r) {
            const int q = q0 + quad * 4 + r;
            mw[r] = pmrow[(size_t)q * (S_ / 64) + (j0 >> 6)];
        }
        __syncthreads();

#pragma unroll
        for (int sub = 0; sub < 4; ++sub) {
            const int rr = sub * 16 + l16;
            const bf16x8 kh0 = *(const bf16x8*)(&Kh[rr][quad * 8]);
            const bf16x8 kh1 = *(const bf16x8*)(&Kh[rr][32 + quad * 8]);
            const bf16x8 kl0 = *(const bf16x8*)(&Kl[rr][quad * 8]);
            const bf16x8 kl1 = *(const bf16x8*)(&Kl[rr][32 + quad * 8]);
            f32x4 c = (f32x4){0.f, 0.f, 0.f, 0.f};
            c = __builtin_amdgcn_mfma_f32_16x16x32_bf16(qh0, kh0, c, 0, 0, 0);
            c = __builtin_amdgcn_mfma_f32_16x16x32_bf16(qh1, kh1, c, 0, 0, 0);
            c = __builtin_amdgcn_mfma_f32_16x16x32_bf16(ql0, kh0, c, 0, 0, 0);
            c = __builtin_amdgcn_mfma_f32_16x16x32_bf16(ql1, kh1, c, 0, 0, 0);
            c = __builtin_amdgcn_mfma_f32_16x16x32_bf16(qh0, kl0, c, 0, 0, 0);
            c = __builtin_amdgcn_mfma_f32_16x16x32_bf16(qh1, kl1, c, 0, 0, 0);
#pragma unroll
            for (int r = 0; r < 4; ++r) {
                const int msk = (int)((mw[r] >> (sub * 16 + l16)) & 1ull);
                lsum[r] += msk ? 0.f : __expf(c[r] * scale);
            }
        }
        __syncthreads();
    }

#pragma unroll
    for (int r = 0; r < 4; ++r) {
        float v = lsum[r];
        v += __shfl_xor(v, 1);
        v += __shfl_xor(v, 2);
        v += __shfl_xor(v, 4);
        v += __shfl_xor(v, 8);
        lsum[r] = v;
    }
    float norm[4];
#pragma unroll
    for (int r = 0; r < 4; ++r) norm[r] = 2048.f / lsum[r];

    // ---------------- Pass 2: weights (single write) + PV ----------------
    f32x4 acc[4];
#pragma unroll
    for (int t = 0; t < 4; ++t) acc[t] = (f32x4){0.f, 0.f, 0.f, 0.f};

    for (int j0 = 0; j0 < S_; j0 += 64) {
        {
            const size_t ko = (size_t)(j0 + srow) * D_ + scol;
            *(bf16x8*)(&Kh[srow][scol])     = *(const bf16x8*)(khst + ko);
            *(bf16x8*)(&Kh[srow][scol + 8]) = *(const bf16x8*)(khst + ko + 8);
            *(bf16x8*)(&Kl[srow][scol])     = *(const bf16x8*)(klst + ko);
            *(bf16x8*)(&Kl[srow][scol + 8]) = *(const bf16x8*)(klst + ko + 8);
            *(bf16x8*)(&vT[srow][scol])     = *(const bf16x8*)(vtst + j0);
            *(bf16x8*)(&vT[srow][scol + 8]) = *(const bf16x8*)(vtst + j0 + 8);
        }
        unsigned long long mw[4];
#pragma unroll
        for (int r = 0; r < 4; ++r) {
            const int q = q0 + quad * 4 + r;
            mw[r] = pmrow[(size_t)q * (S_ / 64) + (j0 >> 6)];
        }
        __syncthreads();

#pragma unroll
        for (int sub = 0; sub < 4; ++sub) {
            const int rr = sub * 16 + l16;
            const bf16x8 kh0 = *(const bf16x8*)(&Kh[rr][quad * 8]);
            const bf16x8 kh1 = *(const bf16x8*)(&Kh[rr][32 + quad * 8]);
            const bf16x8 kl0 = *(const bf16x8*)(&Kl[rr][quad * 8]);
            const bf16x8 kl1 = *(const bf16x8*)(&Kl[rr][32 + quad * 8]);
            f32x4 c = (f32x4){0.f, 0.f, 0.f, 0.f};
            c = __builtin_amdgcn_mfma_f32_16x16x32_bf16(qh0, kh0, c, 0, 0, 0);
            c = __builtin_amdgcn_mfma_f32_16x16x32_bf16(qh1, kh1, c, 0, 0, 0);
            c = __builtin_amdgcn_mfma_f32_16x16x32_bf16(ql0, kh0, c, 0, 0, 0);
            c = __builtin_amdgcn_mfma_f32_16x16x32_bf16(ql1, kh1, c, 0, 0, 0);
            c = __builtin_amdgcn_mfma_f32_16x16x32_bf16(qh0, kl0, c, 0, 0, 0);
            c = __builtin_amdgcn_mfma_f32_16x16x32_bf16(qh1, kl1, c, 0, 0, 0);
            const int jt = j0 + sub * 16;
#pragma unroll
            for (int r = 0; r < 4; ++r) {
                const int q = q0 + quad * 4 + r;
                const int msk = (int)((mw[r] >> (sub * 16 + l16)) & 1ull);
                const float e = msk ? 0.f : __expf(c[r] * scale);
                __builtin_nontemporal_store(e * norm[r],
                    &wout[wbase + (size_t)q * S_ + jt + l16]);
                wl[wave][quad * 4 + r][sub * 16 + l16] = (bf16_t)e;
            }
        }
        // PV with unnormalized bf16 weights (wl is same-wave only; vT synced)
        const bf16x8 wa0 = *(const bf16x8*)(&wl[wave][l16][quad * 8]);
        const bf16x8 wa1 = *(const bf16x8*)(&wl[wave][l16][32 + quad * 8]);
#pragma unroll
        for (int t = 0; t < 4; ++t) {
            const bf16x8 vf0 = *(const bf16x8*)(&vT[t * 16 + l16][quad * 8]);
            const bf16x8 vf1 = *(const bf16x8*)(&vT[t * 16 + l16][32 + quad * 8]);
            acc[t] = __builtin_amdgcn_mfma_f32_16x16x32_bf16(wa0, vf0, acc[t], 0, 0, 0);
            acc[t] = __builtin_amdgcn_mfma_f32_16x16x32_bf16(wa1, vf1, acc[t], 0, 0, 0);
        }
        __syncthreads();
    }

#pragma unroll
    for (int t = 0; t < 4; ++t) {
#pragma unroll
        for (int r = 0; r < 4; ++r) {
            const int q = q0 + quad * 4 + r;
            ctx[((size_t)(b * S_ + q)) * D_ + h * DK_ + t * 16 + l16] =
                (bf16_t)(acc[t][r] * norm[r]);
        }
    }
}

// ---------------------------------------------------------------------------
extern "C" void kernel_launch(void* const* d_in, const int* in_sizes, int n_in,
                              void* d_out, int out_size, void* d_ws, size_t ws_size,
                              hipStream_t stream) {
    const float* Q    = (const float*)d_in[0];
    const float* K    = (const float*)d_in[1];
    const float* V    = (const float*)d_in[2];
    const int*   mask = (const int*)d_in[3];
    const float* Wq   = (const float*)d_in[4];
    const float* bq   = (const float*)d_in[5];
    const float* Wk   = (const float*)d_in[6];
    const float* bk   = (const float*)d_in[7];
    const float* Wv   = (const float*)d_in[8];
    const float* bv   = (const float*)d_in[9];
    const float* Wo   = (const float*)d_in[10];
    const float* bo   = (const float*)d_in[11];

    const size_t BSD = (size_t)B_ * S_ * D_;  // 4,194,304
    float* out  = (float*)d_out;              // [B,S,D] fp32
    float* wout = out + BSD;                  // [B,H,S,S] fp32

    bf16_t* qh = (bf16_t*)d_ws;
    bf16_t* ql = qh + BSD;
    bf16_t* kh = ql + BSD;
    bf16_t* kl = kh + BSD;
    bf16_t* vt = kl + BSD;
    bf16_t* cx = vt + BSD;
    unsigned long long* pk = (unsigned long long*)(cx + BSD);   // 1 MB

    const int M = B_ * S_;   // 4096
    const int N = D_;        // 1024
    const int Kd = D_;       // 1024
    const dim3 ggrid((M / 64) * (N / 64));    // 1024
    const dim3 gblk(256);

    pack_mask<<<dim3(512), gblk, 0, stream>>>(mask, pk);

    gemm_bt<float, OM_SPLIT, true><<<ggrid, gblk, 0, stream>>>(Q, Wq, bq, qh, ql, M, N, Kd);
    gemm_bt<float, OM_SPLIT, true><<<ggrid, gblk, 0, stream>>>(K, Wk, bk, kh, kl, M, N, Kd);
    gemm_bt<float, OM_HEADT, false><<<ggrid, gblk, 0, stream>>>(V, Wv, bv, vt, nullptr, M, N, Kd);

    attn_kernel<<<dim3(B_ * H_ * (S_ / 64)), gblk, 0, stream>>>(
        qh, ql, kh, kl, vt, pk, wout, cx);

    gemm_bt<bf16_t, OM_F32, false><<<ggrid, gblk, 0, stream>>>(cx, Wo, bo, out, nullptr, M, N, Kd);
}